// Round 9
// baseline (219.122 us; speedup 1.0000x reference)
//
#include <hip/hip_runtime.h>

// Problem constants (fixed by the reference)
#define ZBATCH 4
#define PN     512
#define CINC   32
#define COUTC  32
#define EN     65536
#define HIDN   128
#define NNODE  (ZBATCH*PN)   // 2048 nodes
#define CAP    128           // per-node edge bin cap (mean 32, +17 sigma)
#define HP     64            // h-pairs (128 h / 2)
#define WFW    (HP*COUTC)    // 2048 u32 words per node (f16x2 each)

// ===== ATTRIBUTION BUILD: k1_wf/k2/k3 repeat their (idempotent) work rep=4
// times inside the dispatch so each becomes visible in rocprof top-5 with
// counters. rep is a runtime arg -> compiler can't fold the repeats. =====

using hvec2 = decltype(__builtin_amdgcn_cvt_pkrtz(0.f, 0.f));

static __device__ __forceinline__ unsigned packh2(float a, float b) {
  hvec2 h = __builtin_amdgcn_cvt_pkrtz(a, b);   // v_cvt_pkrtz_f16_f32
  unsigned u;
  __builtin_memcpy(&u, &h, 4);
  return u;
}

static __device__ __forceinline__ float dot2acc(unsigned hu, unsigned wu,
                                                float acc) {
  hvec2 a, b;
  __builtin_memcpy(&a, &hu, 4);
  __builtin_memcpy(&b, &wu, 4);
#if __has_builtin(__builtin_amdgcn_fdot2)
  return __builtin_amdgcn_fdot2(a, b, acc, false);   // v_dot2_f32_f16
#else
  acc = fmaf((float)a.x, (float)b.x, acc);
  return fmaf((float)a.y, (float)b.y, acc);
#endif
}

// ---- bin: edges into fixed-capacity src and dst bins (runs ONCE) ----
__global__ __launch_bounds__(256) void bin_k(
    const int* __restrict__ eb, const int* __restrict__ ea,
    const int* __restrict__ ebn, int* __restrict__ cnt_src,
    int* __restrict__ cnt_dst, int* __restrict__ order_src,
    int* __restrict__ order_dst) {
  const int e = blockIdx.x * 256 + threadIdx.x;
  const int zb = eb[e];
  const int ns = zb * PN + ebn[e];
  const int nd = zb * PN + ea[e];
  const int p = atomicAdd(&cnt_src[ns], 1);
  if (p < CAP) order_src[ns * CAP + p] = e;
  const int q = atomicAdd(&cnt_dst[nd], 1);
  if (q < CAP) order_dst[nd * CAP + q] = e;
}

// ---- K1: Wf f16-pair, layout [node][co][hp] ----
__global__ __launch_bounds__(256) void k1_wf(
    const float* __restrict__ F, const float* __restrict__ W2,
    unsigned* __restrict__ Wf, int rep) {
  const int t = threadIdx.x;
  const int b = blockIdx.x;            // 0..511
  const int jt = b & 7, ntile = b >> 3;
  const int hp = t & 63;               // h-pair index 0..63
  const int co = jt * 4 + (t >> 6);    // 0..31
  const float4* rA = (const float4*)(W2 + (size_t)(2 * hp) * (COUTC * CINC)
                                     + co * CINC);
  const float4* rB = (const float4*)(W2 + (size_t)(2 * hp + 1) * (COUTC * CINC)
                                     + co * CINC);
  float4 wa[8], wb[8];
#pragma unroll
  for (int q = 0; q < 8; ++q) { wa[q] = rA[q]; wb[q] = rB[q]; }
  const int n0 = ntile * 32;
  for (int r = 0; r < rep; ++r) {
    const float z = (float)(r >> 6);   // always 0; blocks invariant-hoisting
    for (int n = 0; n < 32; ++n) {
      const float4* fr = (const float4*)(F + (size_t)(n0 + n) * CINC);
      float a0 = z, a1 = 0.f, a2 = 0.f, a3 = 0.f;
      float c0 = z, c1 = 0.f, c2 = 0.f, c3 = 0.f;
#pragma unroll
      for (int q = 0; q < 8; ++q) {
        const float4 f = fr[q];
        a0 = fmaf(f.x, wa[q].x, a0); a1 = fmaf(f.y, wa[q].y, a1);
        a2 = fmaf(f.z, wa[q].z, a2); a3 = fmaf(f.w, wa[q].w, a3);
        c0 = fmaf(f.x, wb[q].x, c0); c1 = fmaf(f.y, wb[q].y, c1);
        c2 = fmaf(f.z, wb[q].z, c2); c3 = fmaf(f.w, wb[q].w, c3);
      }
      Wf[(size_t)(n0 + n) * WFW + co * HP + hp] =
          packh2((a0 + a1) + (a2 + a3), (c0 + c1) + (c2 + c3));
    }
  }
}

// ---- K2: per src node, msg[e][co] = H(e).Wf[n][:][co] via f16 dot2 ----
__global__ __launch_bounds__(256) void k2_msg(
    const float* __restrict__ evec, const float* __restrict__ W1,
    const float* __restrict__ b1, const unsigned* __restrict__ Wf,
    const int* __restrict__ cnt_src, const int* __restrict__ order_src,
    const int* __restrict__ nn, float* __restrict__ msg, int rep) {
  const int n = blockIdx.x;
  const int t = threadIdx.x;
  const int lane = t & 63, w = t >> 6;
  const int co = lane & 31, hh = lane >> 5;

  __shared__ int ords[CAP];
  __shared__ __align__(16) unsigned Hbuf[4][8][64];   // [wave][edge][h-pair]

  const int c0 = cnt_src[n];
  const int count = c0 < CAP ? c0 : CAP;       // block-uniform
  if (count == 0) return;

  uint4 wfv[8];                                 // this lane's 32 wf words
  {
    const uint4* wp = (const uint4*)(Wf + (size_t)n * WFW + co * HP + hh * 32);
#pragma unroll
    for (int q = 0; q < 8; ++q) wfv[q] = wp[q];
  }
  if (t < count) ords[t] = order_src[(size_t)n * CAP + t];
  const int h0 = lane << 1;
  const float2 u0 = *(const float2*)(W1 + 0 * HIDN + h0);
  const float2 u1 = *(const float2*)(W1 + 1 * HIDN + h0);
  const float2 u2 = *(const float2*)(W1 + 2 * HIDN + h0);
  const float2 u3 = *(const float2*)(W1 + 3 * HIDN + h0);
  const float2 b2 = *(const float2*)(b1 + h0);
  const float scale = rsqrtf((float)nn[0]);
  __syncthreads();                              // ords visible

  for (int r = 0; r < rep; ++r) {
    const float z = (float)(r >> 6);            // always 0; anti-hoist
    for (int base = w * 8; base < count; base += 32) {
      int e8[8]; float ex[8], ey[8], ez[8];
#pragma unroll
      for (int i = 0; i < 8; ++i) {
        const int idx = (base + i < count) ? (base + i) : (count - 1);
        e8[i] = ords[idx];
      }
#pragma unroll
      for (int i = 0; i < 8; ++i) {
        ex[i] = evec[3 * e8[i]];
        ey[i] = evec[3 * e8[i] + 1];
        ez[i] = evec[3 * e8[i] + 2];
      }
#pragma unroll
      for (int i = 0; i < 8; ++i) {
        const float r2 = sqrtf(ex[i] * ex[i] + ey[i] * ey[i] + ez[i] * ez[i]);
        const bool bad = (r2 < 1e-10f);
        const float y0 = bad ? 0.f : ex[i], y1 = bad ? 0.f : ey[i];
        const float y2 = bad ? 0.f : ez[i], y3 = bad ? 0.f : r2;
        const float a0 = fmaf(y3, u3.x, fmaf(y2, u2.x,
                         fmaf(y1, u1.x, fmaf(y0, u0.x, b2.x + z))));
        const float a1 = fmaf(y3, u3.y, fmaf(y2, u2.y,
                         fmaf(y1, u1.y, fmaf(y0, u0.y, b2.y))));
        Hbuf[w][i][lane] = packh2(fmaxf(a0, 0.f), fmaxf(a1, 0.f));
      }
      __builtin_amdgcn_wave_barrier();          // wave-private LDS, DS in-order
#pragma unroll
      for (int i = 0; i < 8; ++i) {
        const uint4* hp4 = (const uint4*)&Hbuf[w][i][hh * 32];
        float s0 = z, s1 = 0.f, s2 = 0.f, s3 = 0.f;
#pragma unroll
        for (int q = 0; q < 8; ++q) {
          const uint4 hv = hp4[q];
          s0 = dot2acc(hv.x, wfv[q].x, s0);
          s1 = dot2acc(hv.y, wfv[q].y, s1);
          s2 = dot2acc(hv.z, wfv[q].z, s2);
          s3 = dot2acc(hv.w, wfv[q].w, s3);
        }
        float acc = (s0 + s1) + (s2 + s3);
        acc += __shfl_xor(acc, 32);             // combine the two hh halves
        if (hh == 0 && base + i < count)
          msg[(size_t)e8[i] * COUTC + co] = acc * scale;
      }
      __builtin_amdgcn_wave_barrier();
    }
  }
}

// ---- K3: per dst node (1 wave each), out[n][co] = sum_e msg[e][co] ----
__global__ __launch_bounds__(256) void k3_reduce(
    const float* __restrict__ msg, const int* __restrict__ cnt_dst,
    const int* __restrict__ order_dst, float* __restrict__ out, int rep) {
  const int t = threadIdx.x;
  const int lane = t & 63, w = t >> 6;
  const int co = lane & 31, hh = lane >> 5;
  const int n = blockIdx.x * 4 + w;
  __shared__ int idxs[4][CAP];
  const int c0 = cnt_dst[n];
  const int count = c0 < CAP ? c0 : CAP;
  for (int i = lane; i < count; i += 64)
    idxs[w][i] = order_dst[(size_t)n * CAP + i];
  __builtin_amdgcn_wave_barrier();              // wave-private LDS slice
  for (int r = 0; r < rep; ++r) {
    float a0 = (float)(r >> 6), a1 = 0.f, a2 = 0.f, a3 = 0.f;  // anti-hoist
    for (int g = hh * 4; g < count; g += 8) {
      const int i1 = g + 1, i2 = g + 2, i3 = g + 3;
      a0 += msg[(size_t)idxs[w][g] * COUTC + co];
      if (i1 < count) a1 += msg[(size_t)idxs[w][i1] * COUTC + co];
      if (i2 < count) a2 += msg[(size_t)idxs[w][i2] * COUTC + co];
      if (i3 < count) a3 += msg[(size_t)idxs[w][i3] * COUTC + co];
    }
    float acc = (a0 + a1) + (a2 + a3);
    acc += __shfl_xor(acc, 32);
    if (hh == 0) out[(size_t)n * COUTC + co] = acc;
  }
}

extern "C" void kernel_launch(void* const* d_in, const int* in_sizes, int n_in,
                              void* d_out, int out_size, void* d_ws, size_t ws_size,
                              hipStream_t stream) {
  const float* features   = (const float*)d_in[0];
  const float* edge_vec   = (const float*)d_in[1];
  const float* W1         = (const float*)d_in[2];
  const float* b1         = (const float*)d_in[3];
  const float* W2         = (const float*)d_in[4];
  const int*   edge_batch = (const int*)d_in[5];
  const int*   edge_a     = (const int*)d_in[6];
  const int*   edge_b     = (const int*)d_in[7];
  const int*   n_norm     = (const int*)d_in[8];
  float* out = (float*)d_out;

  char* ws = (char*)d_ws;
  unsigned* Wf = (unsigned*)ws;                                // 16 MiB
  float* msg = (float*)(ws + (size_t)NNODE * WFW * 4);         // 8 MiB
  int* ints = (int*)(ws + (size_t)NNODE * WFW * 4 + (size_t)EN * COUTC * 4);
  int* cnt_src   = ints;                        // NNODE
  int* cnt_dst   = ints + NNODE;                // NNODE
  int* order_src = ints + 2 * NNODE;            // NNODE*CAP
  int* order_dst = order_src + NNODE * CAP;     // NNODE*CAP
  const size_t need = (size_t)NNODE * WFW * 4 + (size_t)EN * COUTC * 4
                    + (size_t)(2 * NNODE + 2 * NNODE * CAP) * 4;
  if (ws_size < need) return;

  const int rep = 4;   // attribution: 4x idempotent work in k1/k2/k3
  (void)hipMemsetAsync(cnt_src, 0, 2 * NNODE * 4, stream);
  bin_k<<<256, 256, 0, stream>>>(edge_batch, edge_a, edge_b, cnt_src, cnt_dst,
                                 order_src, order_dst);
  k1_wf<<<512, 256, 0, stream>>>(features, W2, Wf, rep);
  k2_msg<<<NNODE, 256, 0, stream>>>(edge_vec, W1, b1, Wf, cnt_src, order_src,
                                    n_norm, msg, rep);
  k3_reduce<<<NNODE / 4, 256, 0, stream>>>(msg, cnt_dst, order_dst, out, rep);
}

// Round 10
// 144.293 us; speedup vs baseline: 1.5186x; 1.5186x over previous
//
#include <hip/hip_runtime.h>

// Problem constants (fixed by the reference)
#define ZBATCH 4
#define PN     512
#define CINC   32
#define COUTC  32
#define EN     65536
#define HIDN   128
#define NNODE  (ZBATCH*PN)   // 2048 nodes
#define CAP    128           // per-node edge bin cap (mean 32, +17 sigma)
#define HP     64            // h-pairs (128 h / 2)
#define WFW    (HP*COUTC)    // 2048 u32 words per node (f16x2 each)

using hvec2 = decltype(__builtin_amdgcn_cvt_pkrtz(0.f, 0.f));

static __device__ __forceinline__ unsigned packh2(float a, float b) {
  hvec2 h = __builtin_amdgcn_cvt_pkrtz(a, b);   // v_cvt_pkrtz_f16_f32
  unsigned u;
  __builtin_memcpy(&u, &h, 4);
  return u;
}

static __device__ __forceinline__ float dot2acc(unsigned hu, unsigned wu,
                                                float acc) {
  hvec2 a, b;
  __builtin_memcpy(&a, &hu, 4);
  __builtin_memcpy(&b, &wu, 4);
#if __has_builtin(__builtin_amdgcn_fdot2)
  return __builtin_amdgcn_fdot2(a, b, acc, false);   // v_dot2_f32_f16
#else
  acc = fmaf((float)a.x, (float)b.x, acc);
  return fmaf((float)a.y, (float)b.y, acc);
#endif
}

// ---- K1: blocks [0,256): bin edges by src+dst. blocks [256,768): Wf. ----
__global__ __launch_bounds__(256) void k1_bin_wf(
    const float* __restrict__ F, const float* __restrict__ W2,
    unsigned* __restrict__ Wf, const int* __restrict__ eb,
    const int* __restrict__ ea, const int* __restrict__ ebn,
    int* __restrict__ cnt_src, int* __restrict__ cnt_dst,
    int* __restrict__ order_src, int* __restrict__ order_dst) {
  const int t = threadIdx.x;
  const int b = blockIdx.x;
  if (b < 256) {                       // ---- bin role ----
    const int e = b * 256 + t;
    const int zb = eb[e];
    const int ns = zb * PN + ebn[e];
    const int nd = zb * PN + ea[e];
    const int p = atomicAdd(&cnt_src[ns], 1);
    if (p < CAP) order_src[ns * CAP + p] = e;
    const int q = atomicAdd(&cnt_dst[nd], 1);
    if (q < CAP) order_dst[nd * CAP + q] = e;
    return;
  }
  // ---- Wf role: thread = (hp, co-slice); 32 nodes per block ----
  const int bb = b - 256;              // 0..511
  const int jt = bb & 7, ntile = bb >> 3;
  const int hp = t & 63;               // h-pair index 0..63
  const int co = jt * 4 + (t >> 6);    // 0..31
  const float4* rA = (const float4*)(W2 + (size_t)(2 * hp) * (COUTC * CINC)
                                     + co * CINC);
  const float4* rB = (const float4*)(W2 + (size_t)(2 * hp + 1) * (COUTC * CINC)
                                     + co * CINC);
  float4 wa[8], wb[8];
#pragma unroll
  for (int q = 0; q < 8; ++q) { wa[q] = rA[q]; wb[q] = rB[q]; }
  const int n0 = ntile * 32;
  for (int n = 0; n < 32; ++n) {
    const float4* fr = (const float4*)(F + (size_t)(n0 + n) * CINC); // uniform
    float a0 = 0.f, a1 = 0.f, a2 = 0.f, a3 = 0.f;
    float c0 = 0.f, c1 = 0.f, c2 = 0.f, c3 = 0.f;
#pragma unroll
    for (int q = 0; q < 8; ++q) {
      const float4 f = fr[q];
      a0 = fmaf(f.x, wa[q].x, a0); a1 = fmaf(f.y, wa[q].y, a1);
      a2 = fmaf(f.z, wa[q].z, a2); a3 = fmaf(f.w, wa[q].w, a3);
      c0 = fmaf(f.x, wb[q].x, c0); c1 = fmaf(f.y, wb[q].y, c1);
      c2 = fmaf(f.z, wb[q].z, c2); c3 = fmaf(f.w, wb[q].w, c3);
    }
    Wf[(size_t)(n0 + n) * WFW + co * HP + hp] =
        packh2((a0 + a1) + (a2 + a3), (c0 + c1) + (c2 + c3));
  }
}

// ---- K2: ONE WAVE PER NODE (4 nodes/block). Wave prologue amortizes over
//      ~4 batches; no __syncthreads; next batch's evec gathers issued during
//      current dot phase (software pipeline). ----
__global__ __launch_bounds__(256) void k2_msg(
    const float* __restrict__ evec, const float* __restrict__ W1,
    const float* __restrict__ b1, const unsigned* __restrict__ Wf,
    const int* __restrict__ cnt_src, const int* __restrict__ order_src,
    const int* __restrict__ nn, float* __restrict__ msg) {
  const int t = threadIdx.x;
  const int lane = t & 63, w = t >> 6;
  const int n = blockIdx.x * 4 + w;              // one node per wave
  const int co = lane & 31, hh = lane >> 5;

  __shared__ int ords[4][CAP];
  __shared__ __align__(16) unsigned Hbuf[4][8][64];   // [wave][edge][h-pair]

  const int c0 = cnt_src[n];
  const int count = c0 < CAP ? c0 : CAP;         // wave-uniform
  if (count == 0) return;

  // stage this wave's edge list (wave-private LDS row)
  if (lane < count) ords[w][lane] = order_src[(size_t)n * CAP + lane];
  if (lane + 64 < count) ords[w][lane + 64] = order_src[(size_t)n * CAP + lane + 64];

  uint4 wfv[8];                                   // this lane's 32 wf words
  {
    const uint4* wp = (const uint4*)(Wf + (size_t)n * WFW + co * HP + hh * 32);
#pragma unroll
    for (int q = 0; q < 8; ++q) wfv[q] = wp[q];
  }
  const int h0 = lane << 1;
  const float2 u0 = *(const float2*)(W1 + 0 * HIDN + h0);
  const float2 u1 = *(const float2*)(W1 + 1 * HIDN + h0);
  const float2 u2 = *(const float2*)(W1 + 2 * HIDN + h0);
  const float2 u3 = *(const float2*)(W1 + 3 * HIDN + h0);
  const float2 b2 = *(const float2*)(b1 + h0);
  const float scale = rsqrtf((float)nn[0]);
  __builtin_amdgcn_wave_barrier();               // ords staged (same-wave DS)

  // ---- software pipeline: batch 0 gathers up-front ----
  int e8[8]; float ex[8], ey[8], ez[8];
#pragma unroll
  for (int i = 0; i < 8; ++i) {
    const int idx = (i < count) ? i : (count - 1);
    e8[i] = ords[w][idx];
  }
#pragma unroll
  for (int i = 0; i < 8; ++i) {
    ex[i] = evec[3 * e8[i]];
    ey[i] = evec[3 * e8[i] + 1];
    ez[i] = evec[3 * e8[i] + 2];
  }

  for (int base = 0; base < count; base += 8) {
    // -- H phase: lane computes h-pair, packs f16x2, 1 ds_write per edge --
#pragma unroll
    for (int i = 0; i < 8; ++i) {
      const float r2 = sqrtf(ex[i] * ex[i] + ey[i] * ey[i] + ez[i] * ez[i]);
      const bool bad = (r2 < 1e-10f);
      const float y0 = bad ? 0.f : ex[i], y1 = bad ? 0.f : ey[i];
      const float y2 = bad ? 0.f : ez[i], y3 = bad ? 0.f : r2;
      const float a0 = fmaf(y3, u3.x, fmaf(y2, u2.x,
                       fmaf(y1, u1.x, fmaf(y0, u0.x, b2.x))));
      const float a1 = fmaf(y3, u3.y, fmaf(y2, u2.y,
                       fmaf(y1, u1.y, fmaf(y0, u0.y, b2.y))));
      Hbuf[w][i][lane] = packh2(fmaxf(a0, 0.f), fmaxf(a1, 0.f));
    }
    // -- issue next batch's gathers (overlap with dot phase below) --
    int f8[8]; float fx[8], fy[8], fz[8];
    const int nb = base + 8;
#pragma unroll
    for (int i = 0; i < 8; ++i) {
      const int idx = (nb + i < count) ? (nb + i) : (count - 1);
      f8[i] = ords[w][idx];
    }
#pragma unroll
    for (int i = 0; i < 8; ++i) {
      fx[i] = evec[3 * f8[i]];
      fy[i] = evec[3 * f8[i] + 1];
      fz[i] = evec[3 * f8[i] + 2];
    }
    __builtin_amdgcn_wave_barrier();             // H visible (same-wave DS)
    // -- dot phase: 8 uint4 LDS reads + 32 dot2 per edge, 4 acc chains --
#pragma unroll
    for (int i = 0; i < 8; ++i) {
      const uint4* hp4 = (const uint4*)&Hbuf[w][i][hh * 32];
      float s0 = 0.f, s1 = 0.f, s2 = 0.f, s3 = 0.f;
#pragma unroll
      for (int q = 0; q < 8; ++q) {
        const uint4 hv = hp4[q];
        s0 = dot2acc(hv.x, wfv[q].x, s0);
        s1 = dot2acc(hv.y, wfv[q].y, s1);
        s2 = dot2acc(hv.z, wfv[q].z, s2);
        s3 = dot2acc(hv.w, wfv[q].w, s3);
      }
      float acc = (s0 + s1) + (s2 + s3);
      acc += __shfl_xor(acc, 32);                // combine the two hh halves
      if (hh == 0 && base + i < count)
        msg[(size_t)e8[i] * COUTC + co] = acc * scale;
    }
    __builtin_amdgcn_wave_barrier();
    // -- rotate pipeline regs --
#pragma unroll
    for (int i = 0; i < 8; ++i) {
      e8[i] = f8[i]; ex[i] = fx[i]; ey[i] = fy[i]; ez[i] = fz[i];
    }
  }
}

// ---- K3: per dst node (1 wave each), out[n][co] = sum_e msg[e][co] ----
__global__ __launch_bounds__(256) void k3_reduce(
    const float* __restrict__ msg, const int* __restrict__ cnt_dst,
    const int* __restrict__ order_dst, float* __restrict__ out) {
  const int t = threadIdx.x;
  const int lane = t & 63, w = t >> 6;
  const int co = lane & 31, hh = lane >> 5;
  const int n = blockIdx.x * 4 + w;
  __shared__ int idxs[4][CAP];
  const int c0 = cnt_dst[n];
  const int count = c0 < CAP ? c0 : CAP;
  for (int i = lane; i < count; i += 64)
    idxs[w][i] = order_dst[(size_t)n * CAP + i];
  __builtin_amdgcn_wave_barrier();              // wave-private LDS slice
  float a0 = 0.f, a1 = 0.f, a2 = 0.f, a3 = 0.f;
  for (int g = hh * 4; g < count; g += 8) {     // 4 loads in flight per half
    const int i1 = g + 1, i2 = g + 2, i3 = g + 3;
    a0 += msg[(size_t)idxs[w][g] * COUTC + co];
    if (i1 < count) a1 += msg[(size_t)idxs[w][i1] * COUTC + co];
    if (i2 < count) a2 += msg[(size_t)idxs[w][i2] * COUTC + co];
    if (i3 < count) a3 += msg[(size_t)idxs[w][i3] * COUTC + co];
  }
  float acc = (a0 + a1) + (a2 + a3);
  acc += __shfl_xor(acc, 32);
  if (hh == 0) out[(size_t)n * COUTC + co] = acc;   // all out elems written
}

extern "C" void kernel_launch(void* const* d_in, const int* in_sizes, int n_in,
                              void* d_out, int out_size, void* d_ws, size_t ws_size,
                              hipStream_t stream) {
  const float* features   = (const float*)d_in[0];
  const float* edge_vec   = (const float*)d_in[1];
  const float* W1         = (const float*)d_in[2];
  const float* b1         = (const float*)d_in[3];
  const float* W2         = (const float*)d_in[4];
  const int*   edge_batch = (const int*)d_in[5];
  const int*   edge_a     = (const int*)d_in[6];
  const int*   edge_b     = (const int*)d_in[7];
  const int*   n_norm     = (const int*)d_in[8];
  float* out = (float*)d_out;

  char* ws = (char*)d_ws;
  unsigned* Wf = (unsigned*)ws;                                // 16 MiB
  float* msg = (float*)(ws + (size_t)NNODE * WFW * 4);         // 8 MiB
  int* ints = (int*)(ws + (size_t)NNODE * WFW * 4 + (size_t)EN * COUTC * 4);
  int* cnt_src   = ints;                        // NNODE
  int* cnt_dst   = ints + NNODE;                // NNODE
  int* order_src = ints + 2 * NNODE;            // NNODE*CAP
  int* order_dst = order_src + NNODE * CAP;     // NNODE*CAP
  const size_t need = (size_t)NNODE * WFW * 4 + (size_t)EN * COUTC * 4
                    + (size_t)(2 * NNODE + 2 * NNODE * CAP) * 4;
  if (ws_size < need) return;

  (void)hipMemsetAsync(cnt_src, 0, 2 * NNODE * 4, stream);
  k1_bin_wf<<<256 + 512, 256, 0, stream>>>(features, W2, Wf, edge_batch,
                                           edge_a, edge_b, cnt_src, cnt_dst,
                                           order_src, order_dst);
  k2_msg<<<NNODE / 4, 256, 0, stream>>>(edge_vec, W1, b1, Wf, cnt_src,
                                        order_src, n_norm, msg);
  k3_reduce<<<NNODE / 4, 256, 0, stream>>>(msg, cnt_dst, order_dst, out);
}

// Round 11
// 143.051 us; speedup vs baseline: 1.5318x; 1.0087x over previous
//
#include <hip/hip_runtime.h>

// Problem constants (fixed by the reference)
#define ZBATCH 4
#define PN     512
#define CINC   32
#define COUTC  32
#define EN     65536
#define HIDN   128
#define NNODE  (ZBATCH*PN)   // 2048 nodes
#define CAP    128           // per-node edge bin cap (mean 32, +17 sigma)
#define WFW    2048          // u32 words per node (f16x2), B-fragment order

using hvec2 = decltype(__builtin_amdgcn_cvt_pkrtz(0.f, 0.f));
typedef __attribute__((ext_vector_type(8))) _Float16 f16x8;
typedef __attribute__((ext_vector_type(4))) float f32x4;

static __device__ __forceinline__ unsigned packh2(float a, float b) {
  hvec2 h = __builtin_amdgcn_cvt_pkrtz(a, b);   // v_cvt_pkrtz_f16_f32
  unsigned u;
  __builtin_memcpy(&u, &h, 4);
  return u;
}

// ---- K1: blocks [0,256): bin edges by src+dst. blocks [256,768): Wf in
//      B-fragment order: word(n, hp, co) at flat = (ks*2+nt)*256 + g*64 +
//      col*4 + j  (ks=hp>>4, g=(hp>>2)&3, j=hp&3, nt=co>>4, col=co&15),
//      word = (Wf[2hp][co], Wf[2hp+1][co]) f16x2. ----
__global__ __launch_bounds__(256) void k1_bin_wf(
    const float* __restrict__ F, const float* __restrict__ W2,
    unsigned* __restrict__ Wf, const int* __restrict__ eb,
    const int* __restrict__ ea, const int* __restrict__ ebn,
    int* __restrict__ cnt_src, int* __restrict__ cnt_dst,
    int* __restrict__ order_src, int* __restrict__ order_dst) {
  const int t = threadIdx.x;
  const int b = blockIdx.x;
  if (b < 256) {                       // ---- bin role ----
    const int e = b * 256 + t;
    const int zb = eb[e];
    const int ns = zb * PN + ebn[e];
    const int nd = zb * PN + ea[e];
    const int p = atomicAdd(&cnt_src[ns], 1);
    if (p < CAP) order_src[ns * CAP + p] = e;
    const int q = atomicAdd(&cnt_dst[nd], 1);
    if (q < CAP) order_dst[nd * CAP + q] = e;
    return;
  }
  // ---- Wf role: thread = (hp, co-slice of 4); 32 nodes per block ----
  const int bb = b - 256;              // 0..511
  const int jt = bb & 7, ntile = bb >> 3;
  const int hp = t & 63;               // h-pair 0..63
  const int co = jt * 4 + (t >> 6);    // 0..31
  const int ks = hp >> 4, g = (hp >> 2) & 3, j = hp & 3;
  const int nt = co >> 4, col = co & 15;
  const int flat = (ks * 2 + nt) * 256 + g * 64 + col * 4 + j;
  const float4* rA = (const float4*)(W2 + (size_t)(2 * hp) * (COUTC * CINC)
                                     + co * CINC);
  const float4* rB = (const float4*)(W2 + (size_t)(2 * hp + 1) * (COUTC * CINC)
                                     + co * CINC);
  float4 wa[8], wb[8];
#pragma unroll
  for (int q = 0; q < 8; ++q) { wa[q] = rA[q]; wb[q] = rB[q]; }
  const int n0 = ntile * 32;
  for (int n = 0; n < 32; ++n) {
    const float4* fr = (const float4*)(F + (size_t)(n0 + n) * CINC); // uniform
    float a0 = 0.f, a1 = 0.f, a2 = 0.f, a3 = 0.f;
    float c0 = 0.f, c1 = 0.f, c2 = 0.f, c3 = 0.f;
#pragma unroll
    for (int q = 0; q < 8; ++q) {
      const float4 f = fr[q];
      a0 = fmaf(f.x, wa[q].x, a0); a1 = fmaf(f.y, wa[q].y, a1);
      a2 = fmaf(f.z, wa[q].z, a2); a3 = fmaf(f.w, wa[q].w, a3);
      c0 = fmaf(f.x, wb[q].x, c0); c1 = fmaf(f.y, wb[q].y, c1);
      c2 = fmaf(f.z, wb[q].z, c2); c3 = fmaf(f.w, wb[q].w, c3);
    }
    Wf[(size_t)(n0 + n) * WFW + flat] =
        packh2((a0 + a1) + (a2 + a3), (c0 + c1) + (c2 + c3));
  }
}

// ---- K2: MFMA. One wave per node. Per 16-edge chunk: H -> LDS (swizzled),
//      4 ds_read_b128 A-frags, 8 x mfma_f32_16x16x32_f16, predicated stores.
//      B-frags (Wf) preloaded as 8 coalesced dwordx4 per lane. ----
__global__ __launch_bounds__(256) void k2_msg(
    const float* __restrict__ evec, const float* __restrict__ W1,
    const float* __restrict__ b1, const unsigned* __restrict__ Wf,
    const int* __restrict__ cnt_src, const int* __restrict__ order_src,
    const int* __restrict__ nn, float* __restrict__ msg) {
  const int t = threadIdx.x;
  const int lane = t & 63, w = t >> 6;
  const int n = blockIdx.x * 4 + w;              // one node per wave
  const int col = lane & 15, g = lane >> 4;      // fragment coords

  __shared__ int ords[4][CAP];
  __shared__ __align__(16) unsigned Hb[4][1024]; // 16 edges x 64 words, swz

  const int c0 = cnt_src[n];
  const int count = c0 < CAP ? c0 : CAP;         // wave-uniform
  if (count == 0) return;

  if (lane < count) ords[w][lane] = order_src[(size_t)n * CAP + lane];
  if (lane + 64 < count)
    ords[w][lane + 64] = order_src[(size_t)n * CAP + lane + 64];

  // B fragments: q = ks*2+nt; lane (col,g) reads 4 consecutive words
  f16x8 bf[8];
  {
    const unsigned* wfb = Wf + (size_t)n * WFW + g * 64 + col * 4;
#pragma unroll
    for (int q = 0; q < 8; ++q) {
      const uint4 braw = *(const uint4*)(wfb + q * 256);
      __builtin_memcpy(&bf[q], &braw, 16);
    }
  }
  // W1 rows for this lane's h-pair (h0 = 2*lane)
  const int h0 = lane << 1;
  const float2 u0 = *(const float2*)(W1 + 0 * HIDN + h0);
  const float2 u1 = *(const float2*)(W1 + 1 * HIDN + h0);
  const float2 u2 = *(const float2*)(W1 + 2 * HIDN + h0);
  const float2 u3 = *(const float2*)(W1 + 3 * HIDN + h0);
  const float2 b2 = *(const float2*)(b1 + h0);
  const float scale = rsqrtf((float)nn[0]);
  __builtin_amdgcn_wave_barrier();               // ords staged (same-wave DS)

  const int arow = col;                          // A row = lane&15
  const unsigned axor = (unsigned)((arow & 7) << 2);

  for (int base = 0; base < count; base += 16) {
    // ---- H phase: edge i, lane computes h-pair -> swizzled LDS word ----
#pragma unroll
    for (int i = 0; i < 16; ++i) {
      unsigned word = 0;
      if (base + i < count) {                    // wave-uniform
        const int e = __builtin_amdgcn_readfirstlane(ords[w][base + i]);
        const float x0 = evec[3 * e], x1 = evec[3 * e + 1], x2 = evec[3 * e + 2];
        const float r2 = sqrtf(x0 * x0 + x1 * x1 + x2 * x2);
        const bool bad = (r2 < 1e-10f);
        const float y0 = bad ? 0.f : x0, y1 = bad ? 0.f : x1;
        const float y2 = bad ? 0.f : x2, y3 = bad ? 0.f : r2;
        const float a0 = fmaf(y3, u3.x, fmaf(y2, u2.x,
                         fmaf(y1, u1.x, fmaf(y0, u0.x, b2.x))));
        const float a1 = fmaf(y3, u3.y, fmaf(y2, u2.y,
                         fmaf(y1, u1.y, fmaf(y0, u0.y, b2.y))));
        word = packh2(fmaxf(a0, 0.f), fmaxf(a1, 0.f));
      }
      Hb[w][(unsigned)(i * 64 + lane) ^ ((unsigned)(i & 7) << 2)] = word;
    }
    __builtin_amdgcn_wave_barrier();             // H visible (same-wave DS)
    // ---- MFMA phase: 4 K-steps x 2 N-tiles ----
    f32x4 acc0 = {0.f, 0.f, 0.f, 0.f};
    f32x4 acc1 = {0.f, 0.f, 0.f, 0.f};
#pragma unroll
    for (int ks = 0; ks < 4; ++ks) {
      const unsigned aidx = ((unsigned)(arow * 64 + ks * 16 + g * 4)) ^ axor;
      const uint4 araw = *(const uint4*)&Hb[w][aidx];
      f16x8 af;
      __builtin_memcpy(&af, &araw, 16);
      acc0 = __builtin_amdgcn_mfma_f32_16x16x32_f16(af, bf[ks * 2 + 0], acc0, 0, 0, 0);
      acc1 = __builtin_amdgcn_mfma_f32_16x16x32_f16(af, bf[ks * 2 + 1], acc1, 0, 0, 0);
    }
    __builtin_amdgcn_wave_barrier();
    // ---- store: C layout col=lane&15, row=(lane>>4)*4+reg ----
#pragma unroll
    for (int r = 0; r < 4; ++r) {
      const int row = g * 4 + r;
      const int gi = base + row;
      if (gi < count) {
        const int e = ords[w][gi];
        msg[(size_t)e * COUTC + col]      = acc0[r] * scale;
        msg[(size_t)e * COUTC + 16 + col] = acc1[r] * scale;
      }
    }
    __builtin_amdgcn_wave_barrier();
  }
}

// ---- K3: per dst node (1 wave each), out[n][co] = sum_e msg[e][co] ----
__global__ __launch_bounds__(256) void k3_reduce(
    const float* __restrict__ msg, const int* __restrict__ cnt_dst,
    const int* __restrict__ order_dst, float* __restrict__ out) {
  const int t = threadIdx.x;
  const int lane = t & 63, w = t >> 6;
  const int co = lane & 31, hh = lane >> 5;
  const int n = blockIdx.x * 4 + w;
  __shared__ int idxs[4][CAP];
  const int c0 = cnt_dst[n];
  const int count = c0 < CAP ? c0 : CAP;
  for (int i = lane; i < count; i += 64)
    idxs[w][i] = order_dst[(size_t)n * CAP + i];
  __builtin_amdgcn_wave_barrier();              // wave-private LDS slice
  float a0 = 0.f, a1 = 0.f, a2 = 0.f, a3 = 0.f;
  for (int gq = hh * 4; gq < count; gq += 8) {  // 4 loads in flight per half
    const int i1 = gq + 1, i2 = gq + 2, i3 = gq + 3;
    a0 += msg[(size_t)idxs[w][gq] * COUTC + co];
    if (i1 < count) a1 += msg[(size_t)idxs[w][i1] * COUTC + co];
    if (i2 < count) a2 += msg[(size_t)idxs[w][i2] * COUTC + co];
    if (i3 < count) a3 += msg[(size_t)idxs[w][i3] * COUTC + co];
  }
  float acc = (a0 + a1) + (a2 + a3);
  acc += __shfl_xor(acc, 32);
  if (hh == 0) out[(size_t)n * COUTC + co] = acc;   // all out elems written
}

extern "C" void kernel_launch(void* const* d_in, const int* in_sizes, int n_in,
                              void* d_out, int out_size, void* d_ws, size_t ws_size,
                              hipStream_t stream) {
  const float* features   = (const float*)d_in[0];
  const float* edge_vec   = (const float*)d_in[1];
  const float* W1         = (const float*)d_in[2];
  const float* b1         = (const float*)d_in[3];
  const float* W2         = (const float*)d_in[4];
  const int*   edge_batch = (const int*)d_in[5];
  const int*   edge_a     = (const int*)d_in[6];
  const int*   edge_b     = (const int*)d_in[7];
  const int*   n_norm     = (const int*)d_in[8];
  float* out = (float*)d_out;

  char* ws = (char*)d_ws;
  unsigned* Wf = (unsigned*)ws;                                // 16 MiB
  float* msg = (float*)(ws + (size_t)NNODE * WFW * 4);         // 8 MiB
  int* ints = (int*)(ws + (size_t)NNODE * WFW * 4 + (size_t)EN * COUTC * 4);
  int* cnt_src   = ints;                        // NNODE
  int* cnt_dst   = ints + NNODE;                // NNODE
  int* order_src = ints + 2 * NNODE;            // NNODE*CAP
  int* order_dst = order_src + NNODE * CAP;     // NNODE*CAP
  const size_t need = (size_t)NNODE * WFW * 4 + (size_t)EN * COUTC * 4
                    + (size_t)(2 * NNODE + 2 * NNODE * CAP) * 4;
  if (ws_size < need) return;

  (void)hipMemsetAsync(cnt_src, 0, 2 * NNODE * 4, stream);
  k1_bin_wf<<<256 + 512, 256, 0, stream>>>(features, W2, Wf, edge_batch,
                                           edge_a, edge_b, cnt_src, cnt_dst,
                                           order_src, order_dst);
  k2_msg<<<NNODE / 4, 256, 0, stream>>>(edge_vec, W1, b1, Wf, cnt_src,
                                        order_src, n_norm, msg);
  k3_reduce<<<NNODE / 4, 256, 0, stream>>>(msg, cnt_dst, order_dst, out);
}

// Round 12
// 135.072 us; speedup vs baseline: 1.6223x; 1.0591x over previous
//
#include <hip/hip_runtime.h>

// Problem constants (fixed by the reference)
#define ZBATCH 4
#define PN     512
#define CINC   32
#define COUTC  32
#define EN     65536
#define HIDN   128
#define NNODE  (ZBATCH*PN)   // 2048 nodes
#define CAP    128           // per-node edge bin cap (mean 32, +17 sigma)
#define WFW    2048          // u32 words per node (f16x2), B-fragment order

using hvec2 = decltype(__builtin_amdgcn_cvt_pkrtz(0.f, 0.f));
typedef __attribute__((ext_vector_type(8))) _Float16 f16x8;
typedef __attribute__((ext_vector_type(4))) float f32x4;

static __device__ __forceinline__ unsigned packh2(float a, float b) {
  hvec2 h = __builtin_amdgcn_cvt_pkrtz(a, b);   // v_cvt_pkrtz_f16_f32
  unsigned u;
  __builtin_memcpy(&u, &h, 4);
  return u;
}

// ---- K1: blocks [0,256): bin edges by src+dst. blocks [256,768): Wf in
//      B-fragment order: word(n, hp, co) at flat = (ks*2+nt)*256 + g*64 +
//      col*4 + j  (ks=hp>>4, g=(hp>>2)&3, j=hp&3, nt=co>>4, col=co&15),
//      word = (Wf[2hp][co], Wf[2hp+1][co]) f16x2. ----
__global__ __launch_bounds__(256) void k1_bin_wf(
    const float* __restrict__ F, const float* __restrict__ W2,
    unsigned* __restrict__ Wf, const int* __restrict__ eb,
    const int* __restrict__ ea, const int* __restrict__ ebn,
    int* __restrict__ cnt_src, int* __restrict__ cnt_dst,
    int* __restrict__ order_src, int* __restrict__ order_dst) {
  const int t = threadIdx.x;
  const int b = blockIdx.x;
  if (b < 256) {                       // ---- bin role ----
    const int e = b * 256 + t;
    const int zb = eb[e];
    const int ns = zb * PN + ebn[e];
    const int nd = zb * PN + ea[e];
    const int p = atomicAdd(&cnt_src[ns], 1);
    if (p < CAP) order_src[ns * CAP + p] = e;
    const int q = atomicAdd(&cnt_dst[nd], 1);
    if (q < CAP) order_dst[nd * CAP + q] = e;
    return;
  }
  // ---- Wf role: thread = (hp, co-slice of 4); 32 nodes per block ----
  const int bb = b - 256;              // 0..511
  const int jt = bb & 7, ntile = bb >> 3;
  const int hp = t & 63;               // h-pair 0..63
  const int co = jt * 4 + (t >> 6);    // 0..31
  const int ks = hp >> 4, g = (hp >> 2) & 3, j = hp & 3;
  const int nt = co >> 4, col = co & 15;
  const int flat = (ks * 2 + nt) * 256 + g * 64 + col * 4 + j;
  const float4* rA = (const float4*)(W2 + (size_t)(2 * hp) * (COUTC * CINC)
                                     + co * CINC);
  const float4* rB = (const float4*)(W2 + (size_t)(2 * hp + 1) * (COUTC * CINC)
                                     + co * CINC);
  float4 wa[8], wb[8];
#pragma unroll
  for (int q = 0; q < 8; ++q) { wa[q] = rA[q]; wb[q] = rB[q]; }
  const int n0 = ntile * 32;
  for (int n = 0; n < 32; ++n) {
    const float4* fr = (const float4*)(F + (size_t)(n0 + n) * CINC); // uniform
    float a0 = 0.f, a1 = 0.f, a2 = 0.f, a3 = 0.f;
    float c0 = 0.f, c1 = 0.f, c2 = 0.f, c3 = 0.f;
#pragma unroll
    for (int q = 0; q < 8; ++q) {
      const float4 f = fr[q];
      a0 = fmaf(f.x, wa[q].x, a0); a1 = fmaf(f.y, wa[q].y, a1);
      a2 = fmaf(f.z, wa[q].z, a2); a3 = fmaf(f.w, wa[q].w, a3);
      c0 = fmaf(f.x, wb[q].x, c0); c1 = fmaf(f.y, wb[q].y, c1);
      c2 = fmaf(f.z, wb[q].z, c2); c3 = fmaf(f.w, wb[q].w, c3);
    }
    Wf[(size_t)(n0 + n) * WFW + flat] =
        packh2((a0 + a1) + (a2 + a3), (c0 + c1) + (c2 + c3));
  }
}

// ---- K2: MFMA, 2 waves per node, 2 nodes per block (grid = NNODE/2).
//      Wave q of node n handles 16-edge chunks base = q*16, q*16+32, ...
//      Edge ids live in a register (lanes 0-15); readlane/__shfl broadcast.
//      Per chunk: H->LDS (swizzled), 4 ds_read_b128 A-frags, 8 MFMA,
//      predicated scattered stores. ----
__global__ __launch_bounds__(256) void k2_msg(
    const float* __restrict__ evec, const float* __restrict__ W1,
    const float* __restrict__ b1, const unsigned* __restrict__ Wf,
    const int* __restrict__ cnt_src, const int* __restrict__ order_src,
    const int* __restrict__ nn, float* __restrict__ msg) {
  const int t = threadIdx.x;
  const int lane = t & 63, w = t >> 6;
  const int n = blockIdx.x * 2 + (w >> 1);       // 2 nodes per block
  const int q = w & 1;                           // wave-in-node
  const int col = lane & 15, g = lane >> 4;      // fragment coords

  __shared__ __align__(16) unsigned Hb[4][1024]; // per-wave 16x64 words, swz

  const int c0 = cnt_src[n];
  const int count = c0 < CAP ? c0 : CAP;         // wave-uniform
  if (count <= q * 16) return;                   // nothing for this wave

  // B fragments: q8 = ks*2+nt; lane (col,g) reads 4 consecutive words
  f16x8 bf[8];
  {
    const unsigned* wfb = Wf + (size_t)n * WFW + g * 64 + col * 4;
#pragma unroll
    for (int q8 = 0; q8 < 8; ++q8) {
      const uint4 braw = *(const uint4*)(wfb + q8 * 256);
      __builtin_memcpy(&bf[q8], &braw, 16);
    }
  }
  // W1 rows for this lane's h-pair (h0 = 2*lane)
  const int h0 = lane << 1;
  const float2 u0 = *(const float2*)(W1 + 0 * HIDN + h0);
  const float2 u1 = *(const float2*)(W1 + 1 * HIDN + h0);
  const float2 u2 = *(const float2*)(W1 + 2 * HIDN + h0);
  const float2 u3 = *(const float2*)(W1 + 3 * HIDN + h0);
  const float2 b2 = *(const float2*)(b1 + h0);
  const float scale = rsqrtf((float)nn[0]);

  for (int base = q * 16; base < count; base += 32) {
    // ---- edge ids for this chunk: lanes 0-15 hold ords (clamped) ----
    int ordv = 0;
    if (lane < 16) {
      const int idx = base + lane;
      const int ii = idx < count ? idx : count - 1;
      ordv = order_src[(size_t)n * CAP + ii];
    }
    // ---- H phase: edge i, lane computes h-pair -> swizzled LDS word ----
#pragma unroll
    for (int i = 0; i < 16; ++i) {
      unsigned word = 0;
      if (base + i < count) {                    // wave-uniform
        const int e = __builtin_amdgcn_readlane(ordv, i);   // SGPR broadcast
        const float x0 = evec[3 * e], x1 = evec[3 * e + 1], x2 = evec[3 * e + 2];
        const float r2 = sqrtf(x0 * x0 + x1 * x1 + x2 * x2);
        const bool bad = (r2 < 1e-10f);
        const float y0 = bad ? 0.f : x0, y1 = bad ? 0.f : x1;
        const float y2 = bad ? 0.f : x2, y3 = bad ? 0.f : r2;
        const float a0 = fmaf(y3, u3.x, fmaf(y2, u2.x,
                         fmaf(y1, u1.x, fmaf(y0, u0.x, b2.x))));
        const float a1 = fmaf(y3, u3.y, fmaf(y2, u2.y,
                         fmaf(y1, u1.y, fmaf(y0, u0.y, b2.y))));
        word = packh2(fmaxf(a0, 0.f), fmaxf(a1, 0.f));
      }
      Hb[w][(unsigned)(i * 64 + lane) ^ ((unsigned)(i & 7) << 2)] = word;
    }
    __builtin_amdgcn_wave_barrier();             // H visible (same-wave DS)
    // ---- MFMA phase: 4 K-steps x 2 N-tiles ----
    f32x4 acc0 = {0.f, 0.f, 0.f, 0.f};
    f32x4 acc1 = {0.f, 0.f, 0.f, 0.f};
    const unsigned axor = (unsigned)((col & 7) << 2);
#pragma unroll
    for (int ks = 0; ks < 4; ++ks) {
      const unsigned aidx = ((unsigned)(col * 64 + ks * 16 + g * 4)) ^ axor;
      const uint4 araw = *(const uint4*)&Hb[w][aidx];
      f16x8 af;
      __builtin_memcpy(&af, &araw, 16);
      acc0 = __builtin_amdgcn_mfma_f32_16x16x32_f16(af, bf[ks * 2 + 0], acc0, 0, 0, 0);
      acc1 = __builtin_amdgcn_mfma_f32_16x16x32_f16(af, bf[ks * 2 + 1], acc1, 0, 0, 0);
    }
    __builtin_amdgcn_wave_barrier();
    // ---- store: C layout col=lane&15, row=(lane>>4)*4+reg ----
#pragma unroll
    for (int r = 0; r < 4; ++r) {
      const int row = g * 4 + r;
      const int gi = base + row;
      if (gi < count) {
        const int e = __shfl(ordv, row);
        msg[(size_t)e * COUTC + col]      = acc0[r] * scale;
        msg[(size_t)e * COUTC + 16 + col] = acc1[r] * scale;
      }
    }
    __builtin_amdgcn_wave_barrier();
  }
}

// ---- K3: per dst node (1 wave each), out[n][co] = sum_e msg[e][co] ----
__global__ __launch_bounds__(256) void k3_reduce(
    const float* __restrict__ msg, const int* __restrict__ cnt_dst,
    const int* __restrict__ order_dst, float* __restrict__ out) {
  const int t = threadIdx.x;
  const int lane = t & 63, w = t >> 6;
  const int co = lane & 31, hh = lane >> 5;
  const int n = blockIdx.x * 4 + w;
  __shared__ int idxs[4][CAP];
  const int c0 = cnt_dst[n];
  const int count = c0 < CAP ? c0 : CAP;
  for (int i = lane; i < count; i += 64)
    idxs[w][i] = order_dst[(size_t)n * CAP + i];
  __builtin_amdgcn_wave_barrier();              // wave-private LDS slice
  float a0 = 0.f, a1 = 0.f, a2 = 0.f, a3 = 0.f;
  for (int gq = hh * 4; gq < count; gq += 8) {  // 4 loads in flight per half
    const int i1 = gq + 1, i2 = gq + 2, i3 = gq + 3;
    a0 += msg[(size_t)idxs[w][gq] * COUTC + co];
    if (i1 < count) a1 += msg[(size_t)idxs[w][i1] * COUTC + co];
    if (i2 < count) a2 += msg[(size_t)idxs[w][i2] * COUTC + co];
    if (i3 < count) a3 += msg[(size_t)idxs[w][i3] * COUTC + co];
  }
  float acc = (a0 + a1) + (a2 + a3);
  acc += __shfl_xor(acc, 32);
  if (hh == 0) out[(size_t)n * COUTC + co] = acc;   // all out elems written
}

extern "C" void kernel_launch(void* const* d_in, const int* in_sizes, int n_in,
                              void* d_out, int out_size, void* d_ws, size_t ws_size,
                              hipStream_t stream) {
  const float* features   = (const float*)d_in[0];
  const float* edge_vec   = (const float*)d_in[1];
  const float* W1         = (const float*)d_in[2];
  const float* b1         = (const float*)d_in[3];
  const float* W2         = (const float*)d_in[4];
  const int*   edge_batch = (const int*)d_in[5];
  const int*   edge_a     = (const int*)d_in[6];
  const int*   edge_b     = (const int*)d_in[7];
  const int*   n_norm     = (const int*)d_in[8];
  float* out = (float*)d_out;

  char* ws = (char*)d_ws;
  unsigned* Wf = (unsigned*)ws;                                // 16 MiB
  float* msg = (float*)(ws + (size_t)NNODE * WFW * 4);         // 8 MiB
  int* ints = (int*)(ws + (size_t)NNODE * WFW * 4 + (size_t)EN * COUTC * 4);
  int* cnt_src   = ints;                        // NNODE
  int* cnt_dst   = ints + NNODE;                // NNODE
  int* order_src = ints + 2 * NNODE;            // NNODE*CAP
  int* order_dst = order_src + NNODE * CAP;     // NNODE*CAP
  const size_t need = (size_t)NNODE * WFW * 4 + (size_t)EN * COUTC * 4
                    + (size_t)(2 * NNODE + 2 * NNODE * CAP) * 4;
  if (ws_size < need) return;

  (void)hipMemsetAsync(cnt_src, 0, 2 * NNODE * 4, stream);
  k1_bin_wf<<<256 + 512, 256, 0, stream>>>(features, W2, Wf, edge_batch,
                                           edge_a, edge_b, cnt_src, cnt_dst,
                                           order_src, order_dst);
  k2_msg<<<NNODE / 2, 256, 0, stream>>>(edge_vec, W1, b1, Wf, cnt_src,
                                        order_src, n_norm, msg);
  k3_reduce<<<NNODE / 4, 256, 0, stream>>>(msg, cnt_dst, order_dst, out);
}

// Round 13
// 130.854 us; speedup vs baseline: 1.6746x; 1.0322x over previous
//
#include <hip/hip_runtime.h>

// Problem constants (fixed by the reference)
#define ZBATCH 4
#define PN     512
#define CINC   32
#define COUTC  32
#define EN     65536
#define HIDN   128
#define NNODE  (ZBATCH*PN)   // 2048 nodes
#define CAP    128           // per-node edge bin cap (mean 32, +17 sigma)
#define WFW    2048          // u32 words per node (f16x2), B-fragment order

using hvec2 = decltype(__builtin_amdgcn_cvt_pkrtz(0.f, 0.f));
typedef __attribute__((ext_vector_type(8))) _Float16 f16x8;
typedef __attribute__((ext_vector_type(4))) float f32x4;

static __device__ __forceinline__ unsigned packh2(float a, float b) {
  hvec2 h = __builtin_amdgcn_cvt_pkrtz(a, b);   // v_cvt_pkrtz_f16_f32
  unsigned u;
  __builtin_memcpy(&u, &h, 4);
  return u;
}

// ---- K1: blocks [0,256): bin edges by src+dst. blocks [256,768): Wf in
//      B-fragment order: word(n, hp, co) at flat = (ks*2+nt)*256 + g*64 +
//      col*4 + j  (ks=hp>>4, g=(hp>>2)&3, j=hp&3, nt=co>>4, col=co&15),
//      word = (Wf[2hp][co], Wf[2hp+1][co]) f16x2. ----
__global__ __launch_bounds__(256) void k1_bin_wf(
    const float* __restrict__ F, const float* __restrict__ W2,
    unsigned* __restrict__ Wf, const int* __restrict__ eb,
    const int* __restrict__ ea, const int* __restrict__ ebn,
    int* __restrict__ cnt_src, int* __restrict__ cnt_dst,
    int* __restrict__ order_src, int* __restrict__ order_dst) {
  const int t = threadIdx.x;
  const int b = blockIdx.x;
  if (b < 256) {                       // ---- bin role ----
    const int e = b * 256 + t;
    const int zb = eb[e];
    const int ns = zb * PN + ebn[e];
    const int nd = zb * PN + ea[e];
    const int p = atomicAdd(&cnt_src[ns], 1);
    if (p < CAP) order_src[ns * CAP + p] = e;
    const int q = atomicAdd(&cnt_dst[nd], 1);
    if (q < CAP) order_dst[nd * CAP + q] = e;
    return;
  }
  // ---- Wf role: thread = (hp, co-slice of 4); 32 nodes per block ----
  const int bb = b - 256;              // 0..511
  const int jt = bb & 7, ntile = bb >> 3;
  const int hp = t & 63;               // h-pair 0..63
  const int co = jt * 4 + (t >> 6);    // 0..31
  const int ks = hp >> 4, g = (hp >> 2) & 3, j = hp & 3;
  const int nt = co >> 4, col = co & 15;
  const int flat = (ks * 2 + nt) * 256 + g * 64 + col * 4 + j;
  const float4* rA = (const float4*)(W2 + (size_t)(2 * hp) * (COUTC * CINC)
                                     + co * CINC);
  const float4* rB = (const float4*)(W2 + (size_t)(2 * hp + 1) * (COUTC * CINC)
                                     + co * CINC);
  float4 wa[8], wb[8];
#pragma unroll
  for (int q = 0; q < 8; ++q) { wa[q] = rA[q]; wb[q] = rB[q]; }
  const int n0 = ntile * 32;
  for (int n = 0; n < 32; ++n) {
    const float4* fr = (const float4*)(F + (size_t)(n0 + n) * CINC); // uniform
    float a0 = 0.f, a1 = 0.f, a2 = 0.f, a3 = 0.f;
    float c0 = 0.f, c1 = 0.f, c2 = 0.f, c3 = 0.f;
#pragma unroll
    for (int q = 0; q < 8; ++q) {
      const float4 f = fr[q];
      a0 = fmaf(f.x, wa[q].x, a0); a1 = fmaf(f.y, wa[q].y, a1);
      a2 = fmaf(f.z, wa[q].z, a2); a3 = fmaf(f.w, wa[q].w, a3);
      c0 = fmaf(f.x, wb[q].x, c0); c1 = fmaf(f.y, wb[q].y, c1);
      c2 = fmaf(f.z, wb[q].z, c2); c3 = fmaf(f.w, wb[q].w, c3);
    }
    Wf[(size_t)(n0 + n) * WFW + flat] =
        packh2((a0 + a1) + (a2 + a3), (c0 + c1) + (c2 + c3));
  }
}

// ---- K2: double-MFMA. 2 waves/node, 2 nodes/block. Per 16-edge chunk:
//      (1) lanes 0-15 gather their edge's vec in parallel, build A-frag
//          Xp[16e][32k] (K=4 real + 28 zero);
//      (2) 8x mfma_f32_16x16x32_f16 -> H[16e][128h] (bias in C), relu,
//          cvt f16, store to XOR-swizzled LDS;
//      (3) 4x ds_read_b128 A2-frags + 8 MFMA vs preloaded Wf B-frags;
//      (4) predicated scattered stores via shfl'd edge ids. ----
__global__ __launch_bounds__(256) void k2_msg(
    const float* __restrict__ evec, const float* __restrict__ W1,
    const float* __restrict__ b1, const unsigned* __restrict__ Wf,
    const int* __restrict__ cnt_src, const int* __restrict__ order_src,
    const int* __restrict__ nn, float* __restrict__ msg) {
  const int t = threadIdx.x;
  const int lane = t & 63, w = t >> 6;
  const int n = blockIdx.x * 2 + (w >> 1);       // 2 nodes per block
  const int q = w & 1;                           // wave-in-node
  const int col = lane & 15, g = lane >> 4;      // fragment coords

  __shared__ __align__(16) unsigned short Hb[4][16 * 128];  // f16 [wave][e][h]

  const int c0 = cnt_src[n];
  const int count = c0 < CAP ? c0 : CAP;         // wave-uniform
  if (count <= q * 16) return;                   // nothing for this wave

  // ---- PV B fragments (Wf): lane (col,g) reads 4 consecutive words ----
  f16x8 bf[8];
  {
    const unsigned* wfb = Wf + (size_t)n * WFW + g * 64 + col * 4;
#pragma unroll
    for (int q8 = 0; q8 < 8; ++q8) {
      const uint4 braw = *(const uint4*)(wfb + q8 * 256);
      __builtin_memcpy(&bf[q8], &braw, 16);
    }
  }
  // ---- H-MFMA B fragments (W1 padded K=32) + bias ----
  f16x8 w1b[8];
  float b1v[8];
#pragma unroll
  for (int nt = 0; nt < 8; ++nt) {
    const int h = nt * 16 + col;
    b1v[nt] = b1[h];
    unsigned four[4] = {0u, 0u, 0u, 0u};
    if (g == 0) {                                 // k=0..3 real, rest zero
      four[0] = packh2(W1[h],            W1[HIDN + h]);
      four[1] = packh2(W1[2 * HIDN + h], W1[3 * HIDN + h]);
    }
    __builtin_memcpy(&w1b[nt], four, 16);
  }
  const float scale = rsqrtf((float)nn[0]);
  unsigned short* hbase = &Hb[w][0];

  for (int base = q * 16; base < count; base += 32) {
    // ---- gather: lane l<16 loads edge (base+l)'s vector, builds X row ----
    int ordv = 0;
    float y0 = 0.f, y1 = 0.f, y2 = 0.f, y3 = 0.f;
    if (lane < 16) {
      const int idx = base + lane;
      const int ii = idx < count ? idx : count - 1;
      ordv = order_src[(size_t)n * CAP + ii];
      const float x0 = evec[3 * ordv], x1 = evec[3 * ordv + 1],
                  x2 = evec[3 * ordv + 2];
      const float r2 = sqrtf(x0 * x0 + x1 * x1 + x2 * x2);
      const bool bad = (r2 < 1e-10f);
      y0 = bad ? 0.f : x0; y1 = bad ? 0.f : x1;
      y2 = bad ? 0.f : x2; y3 = bad ? 0.f : r2;
    }
    f16x8 af;
    {
      unsigned four[4] = {0u, 0u, 0u, 0u};
      if (lane < 16) {                            // g==0 <=> lane<16
        four[0] = packh2(y0, y1);
        four[1] = packh2(y2, y3);
      }
      __builtin_memcpy(&af, four, 16);
    }
    // ---- H phase: 8 MFMA tiles, bias in C, relu, f16 -> swizzled LDS ----
#pragma unroll
    for (int nt = 0; nt < 8; ++nt) {
      f32x4 ah = {b1v[nt], b1v[nt], b1v[nt], b1v[nt]};
      ah = __builtin_amdgcn_mfma_f32_16x16x32_f16(af, w1b[nt], ah, 0, 0, 0);
#pragma unroll
      for (int r = 0; r < 4; ++r) {
        const float hv = fmaxf(ah[r], 0.f);       // D[edge=g*4+r][h=nt*16+col]
        const int e = g * 4 + r;
        const unsigned baddr =
            ((unsigned)(e * 256 + (nt * 16 + col) * 2)) ^
            ((unsigned)(e & 7) << 4);
        __fp16 h16 = (__fp16)hv;
        unsigned short bits;
        __builtin_memcpy(&bits, &h16, 2);
        *(unsigned short*)((char*)hbase + baddr) = bits;
      }
    }
    __builtin_amdgcn_wave_barrier();              // H visible (same-wave DS)
    // ---- PV phase: A2[row=col(edge)][k], 4 K-steps x 2 N-tiles ----
    f32x4 acc0 = {0.f, 0.f, 0.f, 0.f};
    f32x4 acc1 = {0.f, 0.f, 0.f, 0.f};
#pragma unroll
    for (int ks = 0; ks < 4; ++ks) {
      const unsigned raddr =
          ((unsigned)(col * 256 + ks * 64 + g * 16)) ^
          ((unsigned)(col & 7) << 4);
      const uint4 araw = *(const uint4*)((char*)hbase + raddr);
      f16x8 a2;
      __builtin_memcpy(&a2, &araw, 16);
      acc0 = __builtin_amdgcn_mfma_f32_16x16x32_f16(a2, bf[ks * 2 + 0], acc0, 0, 0, 0);
      acc1 = __builtin_amdgcn_mfma_f32_16x16x32_f16(a2, bf[ks * 2 + 1], acc1, 0, 0, 0);
    }
    __builtin_amdgcn_wave_barrier();
    // ---- store: C layout col=lane&15, row=(lane>>4)*4+reg ----
#pragma unroll
    for (int r = 0; r < 4; ++r) {
      const int row = g * 4 + r;
      const int gi = base + row;
      if (gi < count) {
        const int e = __shfl(ordv, row);
        msg[(size_t)e * COUTC + col]      = acc0[r] * scale;
        msg[(size_t)e * COUTC + 16 + col] = acc1[r] * scale;
      }
    }
    __builtin_amdgcn_wave_barrier();
  }
}

// ---- K3: per dst node (1 wave each), out[n][co] = sum_e msg[e][co] ----
__global__ __launch_bounds__(256) void k3_reduce(
    const float* __restrict__ msg, const int* __restrict__ cnt_dst,
    const int* __restrict__ order_dst, float* __restrict__ out) {
  const int t = threadIdx.x;
  const int lane = t & 63, w = t >> 6;
  const int co = lane & 31, hh = lane >> 5;
  const int n = blockIdx.x * 4 + w;
  __shared__ int idxs[4][CAP];
  const int c0 = cnt_dst[n];
  const int count = c0 < CAP ? c0 : CAP;
  for (int i = lane; i < count; i += 64)
    idxs[w][i] = order_dst[(size_t)n * CAP + i];
  __builtin_amdgcn_wave_barrier();              // wave-private LDS slice
  float a0 = 0.f, a1 = 0.f, a2 = 0.f, a3 = 0.f;
  for (int gq = hh * 4; gq < count; gq += 8) {  // 4 loads in flight per half
    const int i1 = gq + 1, i2 = gq + 2, i3 = gq + 3;
    a0 += msg[(size_t)idxs[w][gq] * COUTC + co];
    if (i1 < count) a1 += msg[(size_t)idxs[w][i1] * COUTC + co];
    if (i2 < count) a2 += msg[(size_t)idxs[w][i2] * COUTC + co];
    if (i3 < count) a3 += msg[(size_t)idxs[w][i3] * COUTC + co];
  }
  float acc = (a0 + a1) + (a2 + a3);
  acc += __shfl_xor(acc, 32);
  if (hh == 0) out[(size_t)n * COUTC + co] = acc;   // all out elems written
}

extern "C" void kernel_launch(void* const* d_in, const int* in_sizes, int n_in,
                              void* d_out, int out_size, void* d_ws, size_t ws_size,
                              hipStream_t stream) {
  const float* features   = (const float*)d_in[0];
  const float* edge_vec   = (const float*)d_in[1];
  const float* W1         = (const float*)d_in[2];
  const float* b1         = (const float*)d_in[3];
  const float* W2         = (const float*)d_in[4];
  const int*   edge_batch = (const int*)d_in[5];
  const int*   edge_a     = (const int*)d_in[6];
  const int*   edge_b     = (const int*)d_in[7];
  const int*   n_norm     = (const int*)d_in[8];
  float* out = (float*)d_out;

  char* ws = (char*)d_ws;
  unsigned* Wf = (unsigned*)ws;                                // 16 MiB
  float* msg = (float*)(ws + (size_t)NNODE * WFW * 4);         // 8 MiB
  int* ints = (int*)(ws + (size_t)NNODE * WFW * 4 + (size_t)EN * COUTC * 4);
  int* cnt_src   = ints;                        // NNODE
  int* cnt_dst   = ints + NNODE;                // NNODE
  int* order_src = ints + 2 * NNODE;            // NNODE*CAP
  int* order_dst = order_src + NNODE * CAP;     // NNODE*CAP
  const size_t need = (size_t)NNODE * WFW * 4 + (size_t)EN * COUTC * 4
                    + (size_t)(2 * NNODE + 2 * NNODE * CAP) * 4;
  if (ws_size < need) return;

  (void)hipMemsetAsync(cnt_src, 0, 2 * NNODE * 4, stream);
  k1_bin_wf<<<256 + 512, 256, 0, stream>>>(features, W2, Wf, edge_batch,
                                           edge_a, edge_b, cnt_src, cnt_dst,
                                           order_src, order_dst);
  k2_msg<<<NNODE / 2, 256, 0, stream>>>(edge_vec, W1, b1, Wf, cnt_src,
                                        order_src, n_norm, msg);
  k3_reduce<<<NNODE / 4, 256, 0, stream>>>(msg, cnt_dst, order_dst, out);
}

// Round 14
// 130.237 us; speedup vs baseline: 1.6825x; 1.0047x over previous
//
#include <hip/hip_runtime.h>

// Problem constants (fixed by the reference)
#define ZBATCH 4
#define PN     512
#define CINC   32
#define COUTC  32
#define EN     65536
#define HIDN   128
#define NNODE  (ZBATCH*PN)   // 2048 nodes
#define CAP    128           // per-node edge bin cap (mean 32, +17 sigma)
#define WFW    2048          // u32 words per node (f16x2), B-fragment order

using hvec2 = decltype(__builtin_amdgcn_cvt_pkrtz(0.f, 0.f));
typedef __attribute__((ext_vector_type(8))) _Float16 f16x8;
typedef __attribute__((ext_vector_type(4))) float f32x4;

static __device__ __forceinline__ unsigned packh2(float a, float b) {
  hvec2 h = __builtin_amdgcn_cvt_pkrtz(a, b);   // v_cvt_pkrtz_f16_f32
  unsigned u;
  __builtin_memcpy(&u, &h, 4);
  return u;
}

// ---- K1: blocks [0,256): bin edges by src+dst. blocks [256,768): Wf in
//      B-fragment order: word(n, hp, co) at flat = (ks*2+nt)*256 + g*64 +
//      col*4 + j  (ks=hp>>4, g=(hp>>2)&3, j=hp&3, nt=co>>4, col=co&15),
//      word = (Wf[2hp][co], Wf[2hp+1][co]) f16x2. ----
__global__ __launch_bounds__(256) void k1_bin_wf(
    const float* __restrict__ F, const float* __restrict__ W2,
    unsigned* __restrict__ Wf, const int* __restrict__ eb,
    const int* __restrict__ ea, const int* __restrict__ ebn,
    int* __restrict__ cnt_src, int* __restrict__ cnt_dst,
    int* __restrict__ order_src, int* __restrict__ order_dst) {
  const int t = threadIdx.x;
  const int b = blockIdx.x;
  if (b < 256) {                       // ---- bin role ----
    const int e = b * 256 + t;
    const int zb = eb[e];
    const int ns = zb * PN + ebn[e];
    const int nd = zb * PN + ea[e];
    const int p = atomicAdd(&cnt_src[ns], 1);
    if (p < CAP) order_src[ns * CAP + p] = e;
    const int q = atomicAdd(&cnt_dst[nd], 1);
    if (q < CAP) order_dst[nd * CAP + q] = e;
    return;
  }
  // ---- Wf role: thread = (hp, co-slice of 4); 32 nodes per block ----
  const int bb = b - 256;              // 0..511
  const int jt = bb & 7, ntile = bb >> 3;
  const int hp = t & 63;               // h-pair 0..63
  const int co = jt * 4 + (t >> 6);    // 0..31
  const int ks = hp >> 4, g = (hp >> 2) & 3, j = hp & 3;
  const int nt = co >> 4, col = co & 15;
  const int flat = (ks * 2 + nt) * 256 + g * 64 + col * 4 + j;
  const float4* rA = (const float4*)(W2 + (size_t)(2 * hp) * (COUTC * CINC)
                                     + co * CINC);
  const float4* rB = (const float4*)(W2 + (size_t)(2 * hp + 1) * (COUTC * CINC)
                                     + co * CINC);
  float4 wa[8], wb[8];
#pragma unroll
  for (int q = 0; q < 8; ++q) { wa[q] = rA[q]; wb[q] = rB[q]; }
  const int n0 = ntile * 32;
  for (int n = 0; n < 32; ++n) {
    const float4* fr = (const float4*)(F + (size_t)(n0 + n) * CINC); // uniform
    float a0 = 0.f, a1 = 0.f, a2 = 0.f, a3 = 0.f;
    float c0 = 0.f, c1 = 0.f, c2 = 0.f, c3 = 0.f;
#pragma unroll
    for (int q = 0; q < 8; ++q) {
      const float4 f = fr[q];
      a0 = fmaf(f.x, wa[q].x, a0); a1 = fmaf(f.y, wa[q].y, a1);
      a2 = fmaf(f.z, wa[q].z, a2); a3 = fmaf(f.w, wa[q].w, a3);
      c0 = fmaf(f.x, wb[q].x, c0); c1 = fmaf(f.y, wb[q].y, c1);
      c2 = fmaf(f.z, wb[q].z, c2); c3 = fmaf(f.w, wb[q].w, c3);
    }
    Wf[(size_t)(n0 + n) * WFW + flat] =
        packh2((a0 + a1) + (a2 + a3), (c0 + c1) + (c2 + c3));
  }
}

// ---- K2: double-MFMA, H computed TRANSPOSED (A=W1^T, B=X) so each H tile
//      writes one ds_write_b64 per lane (8 total) instead of 32 ds_write_b16.
//      2 waves/node, 2 nodes/block. PV phase unchanged. ----
__global__ __launch_bounds__(256) void k2_msg(
    const float* __restrict__ evec, const float* __restrict__ W1,
    const float* __restrict__ b1, const unsigned* __restrict__ Wf,
    const int* __restrict__ cnt_src, const int* __restrict__ order_src,
    const int* __restrict__ nn, float* __restrict__ msg) {
  const int t = threadIdx.x;
  const int lane = t & 63, w = t >> 6;
  const int n = blockIdx.x * 2 + (w >> 1);       // 2 nodes per block
  const int q = w & 1;                           // wave-in-node
  const int col = lane & 15, g = lane >> 4;      // fragment coords

  __shared__ __align__(16) unsigned short Hb[4][16 * 128];  // f16 [wave][e][h]

  const int c0 = cnt_src[n];
  const int count = c0 < CAP ? c0 : CAP;         // wave-uniform
  if (count <= q * 16) return;                   // nothing for this wave

  // ---- PV B fragments (Wf): lane (col,g) reads 4 consecutive words ----
  f16x8 bf[8];
  {
    const unsigned* wfb = Wf + (size_t)n * WFW + g * 64 + col * 4;
#pragma unroll
    for (int q8 = 0; q8 < 8; ++q8) {
      const uint4 braw = *(const uint4*)(wfb + q8 * 256);
      __builtin_memcpy(&bf[q8], &braw, 16);
    }
  }
  // ---- H-MFMA A fragments: W1^T[h][k] (K=4 real of 32) + bias quad ----
  f16x8 w1a[8];
  float4 b1q[8];
#pragma unroll
  for (int nt = 0; nt < 8; ++nt) {
    const int h = nt * 16 + col;                  // A row = col
    b1q[nt] = *(const float4*)(b1 + nt * 16 + g * 4);   // bias for D rows
    unsigned four[4] = {0u, 0u, 0u, 0u};
    if (g == 0) {                                 // k=0..3 real, rest zero
      four[0] = packh2(W1[h],            W1[HIDN + h]);
      four[1] = packh2(W1[2 * HIDN + h], W1[3 * HIDN + h]);
    }
    __builtin_memcpy(&w1a[nt], four, 16);
  }
  const float scale = rsqrtf((float)nn[0]);
  unsigned short* hbase = &Hb[w][0];

  for (int base = q * 16; base < count; base += 32) {
    // ---- gather: lane l<16 loads edge (base+l)'s vector, builds X col ----
    int ordv = 0;
    float y0 = 0.f, y1 = 0.f, y2 = 0.f, y3 = 0.f;
    if (lane < 16) {
      const int idx = base + lane;
      const int ii = idx < count ? idx : count - 1;
      ordv = order_src[(size_t)n * CAP + ii];
      const float x0 = evec[3 * ordv], x1 = evec[3 * ordv + 1],
                  x2 = evec[3 * ordv + 2];
      const float r2 = sqrtf(x0 * x0 + x1 * x1 + x2 * x2);
      const bool bad = (r2 < 1e-10f);
      y0 = bad ? 0.f : x0; y1 = bad ? 0.f : x1;
      y2 = bad ? 0.f : x2; y3 = bad ? 0.f : r2;
    }
    f16x8 xf;                                     // B operand: B[col=e][k]
    {
      unsigned four[4] = {0u, 0u, 0u, 0u};
      if (lane < 16) {                            // g==0 <=> lane<16
        four[0] = packh2(y0, y1);
        four[1] = packh2(y2, y3);
      }
      __builtin_memcpy(&xf, four, 16);
    }
    // ---- H phase: D[row=h-sub][col=edge]; relu; one b64 write per tile ----
#pragma unroll
    for (int nt = 0; nt < 8; ++nt) {
      f32x4 ah = {b1q[nt].x, b1q[nt].y, b1q[nt].z, b1q[nt].w};
      ah = __builtin_amdgcn_mfma_f32_16x16x32_f16(w1a[nt], xf, ah, 0, 0, 0);
      uint2 v;
      v.x = packh2(fmaxf(ah[0], 0.f), fmaxf(ah[1], 0.f));
      v.y = packh2(fmaxf(ah[2], 0.f), fmaxf(ah[3], 0.f));
      // LDS [e=col][h = nt*16 + g*4 + 0..3], byte addr, row-XOR swizzle
      const unsigned baddr =
          ((unsigned)(col * 256 + nt * 32 + g * 8)) ^ ((unsigned)(col & 7) << 4);
      *(uint2*)((char*)hbase + baddr) = v;
    }
    __builtin_amdgcn_wave_barrier();              // H visible (same-wave DS)
    // ---- PV phase: A2[row=edge=col][k], 4 K-steps x 2 N-tiles ----
    f32x4 acc0 = {0.f, 0.f, 0.f, 0.f};
    f32x4 acc1 = {0.f, 0.f, 0.f, 0.f};
#pragma unroll
    for (int ks = 0; ks < 4; ++ks) {
      const unsigned raddr =
          ((unsigned)(col * 256 + ks * 64 + g * 16)) ^
          ((unsigned)(col & 7) << 4);
      const uint4 araw = *(const uint4*)((char*)hbase + raddr);
      f16x8 a2;
      __builtin_memcpy(&a2, &araw, 16);
      acc0 = __builtin_amdgcn_mfma_f32_16x16x32_f16(a2, bf[ks * 2 + 0], acc0, 0, 0, 0);
      acc1 = __builtin_amdgcn_mfma_f32_16x16x32_f16(a2, bf[ks * 2 + 1], acc1, 0, 0, 0);
    }
    __builtin_amdgcn_wave_barrier();
    // ---- store: C layout col=lane&15, row=(lane>>4)*4+reg ----
#pragma unroll
    for (int r = 0; r < 4; ++r) {
      const int row = g * 4 + r;
      const int gi = base + row;
      if (gi < count) {
        const int e = __shfl(ordv, row);
        msg[(size_t)e * COUTC + col]      = acc0[r] * scale;
        msg[(size_t)e * COUTC + 16 + col] = acc1[r] * scale;
      }
    }
    __builtin_amdgcn_wave_barrier();
  }
}

// ---- K3: per dst node (1 wave each), out[n][co] = sum_e msg[e][co] ----
__global__ __launch_bounds__(256) void k3_reduce(
    const float* __restrict__ msg, const int* __restrict__ cnt_dst,
    const int* __restrict__ order_dst, float* __restrict__ out) {
  const int t = threadIdx.x;
  const int lane = t & 63, w = t >> 6;
  const int co = lane & 31, hh = lane >> 5;
  const int n = blockIdx.x * 4 + w;
  __shared__ int idxs[4][CAP];
  const int c0 = cnt_dst[n];
  const int count = c0 < CAP ? c0 : CAP;
  for (int i = lane; i < count; i += 64)
    idxs[w][i] = order_dst[(size_t)n * CAP + i];
  __builtin_amdgcn_wave_barrier();              // wave-private LDS slice
  float a0 = 0.f, a1 = 0.f, a2 = 0.f, a3 = 0.f;
  for (int gq = hh * 4; gq < count; gq += 8) {  // 4 loads in flight per half
    const int i1 = gq + 1, i2 = gq + 2, i3 = gq + 3;
    a0 += msg[(size_t)idxs[w][gq] * COUTC + co];
    if (i1 < count) a1 += msg[(size_t)idxs[w][i1] * COUTC + co];
    if (i2 < count) a2 += msg[(size_t)idxs[w][i2] * COUTC + co];
    if (i3 < count) a3 += msg[(size_t)idxs[w][i3] * COUTC + co];
  }
  float acc = (a0 + a1) + (a2 + a3);
  acc += __shfl_xor(acc, 32);
  if (hh == 0) out[(size_t)n * COUTC + co] = acc;   // all out elems written
}

extern "C" void kernel_launch(void* const* d_in, const int* in_sizes, int n_in,
                              void* d_out, int out_size, void* d_ws, size_t ws_size,
                              hipStream_t stream) {
  const float* features   = (const float*)d_in[0];
  const float* edge_vec   = (const float*)d_in[1];
  const float* W1         = (const float*)d_in[2];
  const float* b1         = (const float*)d_in[3];
  const float* W2         = (const float*)d_in[4];
  const int*   edge_batch = (const int*)d_in[5];
  const int*   edge_a     = (const int*)d_in[6];
  const int*   edge_b     = (const int*)d_in[7];
  const int*   n_norm     = (const int*)d_in[8];
  float* out = (float*)d_out;

  char* ws = (char*)d_ws;
  unsigned* Wf = (unsigned*)ws;                                // 16 MiB
  float* msg = (float*)(ws + (size_t)NNODE * WFW * 4);         // 8 MiB
  int* ints = (int*)(ws + (size_t)NNODE * WFW * 4 + (size_t)EN * COUTC * 4);
  int* cnt_src   = ints;                        // NNODE
  int* cnt_dst   = ints + NNODE;                // NNODE
  int* order_src = ints + 2 * NNODE;            // NNODE*CAP
  int* order_dst = order_src + NNODE * CAP;     // NNODE*CAP
  const size_t need = (size_t)NNODE * WFW * 4 + (size_t)EN * COUTC * 4
                    + (size_t)(2 * NNODE + 2 * NNODE * CAP) * 4;
  if (ws_size < need) return;

  (void)hipMemsetAsync(cnt_src, 0, 2 * NNODE * 4, stream);
  k1_bin_wf<<<256 + 512, 256, 0, stream>>>(features, W2, Wf, edge_batch,
                                           edge_a, edge_b, cnt_src, cnt_dst,
                                           order_src, order_dst);
  k2_msg<<<NNODE / 2, 256, 0, stream>>>(edge_vec, W1, b1, Wf, cnt_src,
                                        order_src, n_norm, msg);
  k3_reduce<<<NNODE / 4, 256, 0, stream>>>(msg, cnt_dst, order_dst, out);
}